// Round 4
// baseline (724.097 us; speedup 1.0000x reference)
//
#include <hip/hip_runtime.h>
#include <math.h>

// Model dims
#define CB 128   // batch
#define CN 5     // n_vars
#define CL 128   // seq len
#define CS 8     // patch size
#define CP 16    // n_patches
#define CD 64    // d_hidden
#define CDT 16   // d_time
#define CDIN 17  // DT+1
#define CNF 63   // D-1
#define CNC 39   // n_classes

__device__ __forceinline__ float wave_sum(float v) {
    v += __shfl_xor(v, 32);
    v += __shfl_xor(v, 16);
    v += __shfl_xor(v, 8);
    v += __shfl_xor(v, 4);
    v += __shfl_xor(v, 2);
    v += __shfl_xor(v, 1);
    return v;
}

// ---------------------------------------------------------------------------
// prep: all weight transposes, coalesced-read / scattered-write.
// Target layouts put the lane dimension (filter / out-channel) contiguous.
// ---------------------------------------------------------------------------
__global__ void prep_kernel(
    const float* __restrict__ mf_w1, const float* __restrict__ mf_w2,
    const float* __restrict__ mf_b2, const float* __restrict__ fp_w,
    const float* __restrict__ attn_in_w, const float* __restrict__ attn_out_w,
    const float* __restrict__ ffn_w1, const float* __restrict__ ffn_w2,
    const float* __restrict__ gnn_W, const float* __restrict__ gsl_Wd1,
    const float* __restrict__ gsl_Wd2,
    const float* __restrict__ ow1, const float* __restrict__ ow2,
    const float* __restrict__ ow3,
    float* __restrict__ w1c16, float* __restrict__ w2t, float* __restrict__ b2t,
    float* __restrict__ fp_wt, float* __restrict__ wit, float* __restrict__ wot,
    float* __restrict__ fw1t, float* __restrict__ fw2t,
    float* __restrict__ gWt, float* __restrict__ Wd1t, float* __restrict__ Wd2t,
    float* __restrict__ o1t, float* __restrict__ o2t, float* __restrict__ o3t) {
    int idx = blockIdx.x * 256 + threadIdx.x;
    if (idx < 65536) {                        // fp_wt[j*64+d] = fp_w[d][j]
        int d = idx >> 10, j = idx & 1023;
        fp_wt[j * 64 + d] = fp_w[idx];
    }
    if (idx < 18496) {                        // w2t[(k*17+j)*64+f] = w2[f][k][j]
        int f = idx / 289, rem = idx % 289;
        w2t[rem * 64 + f] = (f < CNF) ? mf_w2[idx] : 0.f;
    }
    if (idx < 1088) {                         // b2t[r*64+f] = b2[f][r]; w1c16[r*64+f] = w1[f][r][16]
        int f = idx / 17, r = idx % 17;
        b2t[r * 64 + f]   = (f < CNF) ? mf_b2[idx] : 0.f;
        w1c16[r * 64 + f] = (f < CNF) ? mf_w1[idx * 17 + 16] : 0.f;
    }
    if (idx < 24576) {                        // wit[bk][d*192+oc] = wi[bk][oc][d]
        int bk = idx / 12288, rem = idx % 12288;
        int oc = rem >> 6, d = rem & 63;
        wit[bk * 12288 + d * 192 + oc] = attn_in_w[idx];
    }
    if (idx < 8192) {                         // wot[bk][c*64+d] = wo[bk][d][c]
        int bk = idx >> 12, rem = idx & 4095;
        int d = rem >> 6, c = rem & 63;
        wot[bk * 4096 + c * 64 + d] = attn_out_w[idx];
    }
    if (idx < 16384) {                        // fw1t[bk][d*128+c] = fw1[bk][c][d]
        int bk = idx >> 13, rem = idx & 8191;
        int c = rem >> 6, d = rem & 63;
        fw1t[bk * 8192 + d * 128 + c] = ffn_w1[idx];
    }
    if (idx < 16384) {                        // fw2t[bk][c*64+d] = fw2[bk][d][c]
        int bk = idx >> 13, rem = idx & 8191;
        int d = rem >> 7, c = rem & 127;
        fw2t[bk * 8192 + c * 64 + d] = ffn_w2[idx];
    }
    if (idx < 24576) {                        // gWt[bk][m][c*64+o] = gW[bk][m][o][c]
        int bk = idx / 12288, rem = idx % 12288;
        int m = rem >> 12, r2 = rem & 4095;
        int o = r2 >> 6, c = r2 & 63;
        gWt[bk * 12288 + m * 4096 + c * 64 + o] = gnn_W[idx];
    }
    if (idx < 2048) {                         // Wd1t[bk][d*16+l] = Wd1[bk][l][d]
        int bk = idx >> 10, rem = idx & 1023;
        int l = rem >> 6, d = rem & 63;
        Wd1t[bk * 1024 + d * 16 + l] = gsl_Wd1[idx];
        Wd2t[bk * 1024 + d * 16 + l] = gsl_Wd2[idx];
    }
    if (idx < 25600) {                        // o1t[n][i*64+o] = ow1[n][o][i]
        int n = idx / 5120, rem = idx % 5120;
        int o = rem / 80, i = rem % 80;
        o1t[n * 5120 + i * 64 + o] = ow1[idx];
    }
    if (idx < 20480) {                        // o2t[n][i*64+o] = ow2[n][o][i]
        int n = idx >> 12, rem = idx & 4095;
        int o = rem >> 6, i = rem & 63;
        o2t[n * 4096 + i * 64 + o] = ow2[idx];
    }
    if (idx < 12480) {                        // o3t[n][i*64+o] = ow3[n][o][i], o<39
        int n = idx / 2496, rem = idx % 2496;
        int o = rem >> 6, i = rem & 63;
        o3t[n * 4096 + i * 64 + o] = ow3[idx];
    }
}

// ---------------------------------------------------------------------------
// prep2: t_rel is batch-invariant, so the te-part of TTCN phase A is shared
// by all B*N tokens. Emit base in [p][j][s][f] order (contiguous per p) and
// te_tab[p][s][k].
// ---------------------------------------------------------------------------
__global__ __launch_bounds__(64) void prep2_kernel(
    const float* __restrict__ t_rel, const float* __restrict__ omega, const float* __restrict__ alpha,
    const float* __restrict__ mf_w1, const float* __restrict__ mf_b1,
    float* __restrict__ base, float* __restrict__ te_tab) {
    const int blk = blockIdx.x;               // = (p*8+s)*17 + j
    const int j = blk % 17;
    const int ps = blk / 17;                  // p*8+s
    const int p = ps >> 3, s = ps & 7;
    const int f = threadIdx.x;

    const float t = t_rel[p * CS + s];        // row b=0
    float te[16];
#pragma unroll
    for (int i = 0; i < 16; ++i)
        te[i] = (i == 0) ? (omega[0] * t + alpha[0]) : sinf(omega[i] * t + alpha[i]);

    float acc = 0.f;
    if (f < CNF) {
        acc = mf_b1[f * 17 + j];
        const float* w = mf_w1 + (f * 17 + j) * 17;
#pragma unroll
        for (int i = 0; i < 16; ++i) acc = fmaf(te[i], w[i], acc);
    }
    base[((p * 17 + j) * 8 + s) * 64 + f] = acc;

    if (j == 0 && f < 16) te_tab[ps * 16 + f] = te[f];
}

// ---------------------------------------------------------------------------
// TTCN v3: 512-thread blocks (8 waves = 8 tokens sharing one patch index p).
// base/w1c/b2t/te staged in LDS (44 KB -> 3 blocks/CU = 24 waves/CU).
// k split into 4 chunks so live accumulators stay <= 40 (no spills).
// w2t streamed from global: all 8 waves read the same ~22KB/chunk -> L1-hot.
// ---------------------------------------------------------------------------
template <int K0, int KC>
__device__ __forceinline__ float ttcn_chunk(
    const float* __restrict__ w2t, const float* bse, const float* w1c,
    const float* b2s, const float* tes, const float v_s[8], int lane) {
    float lg[KC][8];
#pragma unroll
    for (int kk = 0; kk < KC; ++kk) {
        float bb = b2s[(K0 + kk) * 64 + lane];
#pragma unroll
        for (int s = 0; s < 8; ++s) lg[kk][s] = bb;
    }
#pragma unroll 1
    for (int j = 0; j < 17; ++j) {
        float w1 = w1c[j * 64 + lane];
        float h_s[8];
#pragma unroll
        for (int s = 0; s < 8; ++s)
            h_s[s] = fmaxf(fmaf(v_s[s], w1, bse[(j * 8 + s) * 64 + lane]), 0.f);
#pragma unroll
        for (int kk = 0; kk < KC; ++kk) {
            float w2 = w2t[((K0 + kk) * 17 + j) * 64 + lane];
#pragma unroll
            for (int s = 0; s < 8; ++s) lg[kk][s] = fmaf(h_s[s], w2, lg[kk][s]);
        }
    }
    float out = 0.f;
#pragma unroll
    for (int kk = 0; kk < KC; ++kk) {
        const int k = K0 + kk;
        float m = lg[kk][0];
#pragma unroll
        for (int s = 1; s < 8; ++s) m = fmaxf(m, lg[kk][s]);
        float l = 0.f, o = 0.f;
#pragma unroll
        for (int s = 0; s < 8; ++s) {
            float e = __expf(lg[kk][s] - m);
            l += e;
            o = fmaf(e, (k < 16) ? tes[s * 16 + k] : v_s[s], o);
        }
        out += o / l;
    }
    return out;
}

__global__ __launch_bounds__(512, 6) void ttcn_kernel(
    const float* __restrict__ x, const float* __restrict__ base,
    const float* __restrict__ te_tab, const float* __restrict__ w1c16,
    const float* __restrict__ w2t, const float* __restrict__ b2t,
    const float* __restrict__ pos_enc, float* __restrict__ hout) {
    __shared__ float bse[8704];    // [j][s][f]
    __shared__ float w1c[1088];    // [j][f]
    __shared__ float b2s[1088];    // [k][f]
    __shared__ float tes[128];     // [s][k]
    const int tid = threadIdx.x;
    const int p = blockIdx.x / 80, g = blockIdx.x % 80;

    const float* bsrc = base + p * 8704;
    for (int i = tid; i < 8704; i += 512) bse[i] = bsrc[i];
    for (int i = tid; i < 1088; i += 512) { w1c[i] = w1c16[i]; b2s[i] = b2t[i]; }
    if (tid < 128) tes[tid] = te_tab[p * 128 + tid];
    __syncthreads();

    const int wid = tid >> 6, lane = tid & 63;
    const int bn = g * 8 + wid;          // b*5+n
    const int tok = bn * 16 + p;

    float v_s[8];
#pragma unroll
    for (int s = 0; s < 8; ++s) v_s[s] = x[tok * 8 + s];

    float out = 0.f;
    out += ttcn_chunk<0, 5>(w2t, bse, w1c, b2s, tes, v_s, lane);
    out += ttcn_chunk<5, 4>(w2t, bse, w1c, b2s, tes, v_s, lane);
    out += ttcn_chunk<9, 4>(w2t, bse, w1c, b2s, tes, v_s, lane);
    out += ttcn_chunk<13, 4>(w2t, bse, w1c, b2s, tes, v_s, lane);

    float val = (lane < CNF) ? out : 1.0f;
    hout[tok * 64 + lane] = val + pos_enc[p * 64 + lane];
}

// ---------------------------------------------------------------------------
// Intra-series transformer block: one 256-thread block per (b,n) row.
// ---------------------------------------------------------------------------
__global__ __launch_bounds__(256) void intra_kernel(
    float* __restrict__ h,
    const float* __restrict__ wit, const float* __restrict__ bi,
    const float* __restrict__ wot, const float* __restrict__ bo,
    const float* __restrict__ g1, const float* __restrict__ be1,
    const float* __restrict__ fw1t, const float* __restrict__ fb1,
    const float* __restrict__ fw2t, const float* __restrict__ fb2,
    const float* __restrict__ g2, const float* __restrict__ be2) {
    __shared__ float xs[16][64];
    __shared__ float qs[16][64];
    __shared__ float ks[16][64];
    __shared__ float vs[16][64];
    __shared__ float sc[4][16][16];
    __shared__ float os[16][64];
    __shared__ float x1[16][64];
    __shared__ float fs[16][128];

    const int row = blockIdx.x;  // b*5+n
    float* xin = h + row * CP * CD;
    const int t = threadIdx.x;

    for (int e = t; e < 1024; e += 256) xs[e >> 6][e & 63] = xin[e];
    __syncthreads();

    // qkv: lane = out channel oc (192 active); xs broadcast, wit coalesced
    if (t < 192) {
        const int oc = t;
        float acc[16];
#pragma unroll
        for (int p = 0; p < 16; ++p) acc[p] = bi[oc];
        for (int d = 0; d < 64; ++d) {
            float w = wit[d * 192 + oc];
#pragma unroll
            for (int p = 0; p < 16; ++p) acc[p] = fmaf(xs[p][d], w, acc[p]);
        }
#pragma unroll
        for (int p = 0; p < 16; ++p) {
            if (oc < 64)       qs[p][oc] = acc[p];
            else if (oc < 128) ks[p][oc - 64] = acc[p];
            else               vs[p][oc - 128] = acc[p];
        }
    }
    __syncthreads();

    // scores (4 heads x 16 x 16)
    for (int e = t; e < 1024; e += 256) {
        int hh = e >> 8, i = (e >> 4) & 15, j = e & 15;
        float acc = 0.f;
        for (int d = 0; d < 16; ++d) acc = fmaf(qs[i][hh * 16 + d], ks[j][hh * 16 + d], acc);
        sc[hh][i][j] = acc * 0.25f;  // 1/sqrt(16)
    }
    __syncthreads();

    // softmax over j per (head,i)
    if (t < 64) {
        int hh = t >> 4, i = t & 15;
        float m = sc[hh][i][0];
#pragma unroll
        for (int j = 1; j < 16; ++j) m = fmaxf(m, sc[hh][i][j]);
        float e_[16];
        float l = 0.f;
#pragma unroll
        for (int j = 0; j < 16; ++j) { e_[j] = __expf(sc[hh][i][j] - m); l += e_[j]; }
        float inv = 1.f / l;
#pragma unroll
        for (int j = 0; j < 16; ++j) sc[hh][i][j] = e_[j] * inv;
    }
    __syncthreads();

    // attn out
    for (int e = t; e < 1024; e += 256) {
        int p = e >> 6, c = e & 63, hh = c >> 4;
        float acc = 0.f;
        for (int j = 0; j < 16; ++j) acc = fmaf(sc[hh][p][j], vs[j][c], acc);
        os[p][c] = acc;
    }
    __syncthreads();

    // proj + residual (wot coalesced, os broadcast)
    for (int e = t; e < 1024; e += 256) {
        int p = e >> 6, d = e & 63;
        float acc = bo[d];
        for (int c = 0; c < 64; ++c) acc = fmaf(os[p][c], wot[c * 64 + d], acc);
        x1[p][d] = acc + xs[p][d];
    }
    __syncthreads();

    // LN1
    {
        int w = t >> 6, lane = t & 63;
        for (int p = w; p < 16; p += 4) {
            float v = x1[p][lane];
            float mu = wave_sum(v) * (1.f / 64);
            float d = v - mu;
            float var = wave_sum(d * d) * (1.f / 64);
            x1[p][lane] = d * rsqrtf(var + 1e-5f) * g1[lane] + be1[lane];
        }
    }
    __syncthreads();

    // FFN1
    for (int e = t; e < 2048; e += 256) {
        int p = e >> 7, c = e & 127;
        float acc = fb1[c];
        for (int d = 0; d < 64; ++d) acc = fmaf(x1[p][d], fw1t[d * 128 + c], acc);
        fs[p][c] = fmaxf(acc, 0.f);
    }
    __syncthreads();

    // FFN2 + residual
    for (int e = t; e < 1024; e += 256) {
        int p = e >> 6, d = e & 63;
        float acc = fb2[d];
        for (int c = 0; c < 128; ++c) acc = fmaf(fs[p][c], fw2t[c * 64 + d], acc);
        os[p][d] = acc + x1[p][d];
    }
    __syncthreads();

    // LN2 + write back
    {
        int w = t >> 6, lane = t & 63;
        for (int p = w; p < 16; p += 4) {
            float v = os[p][lane];
            float mu = wave_sum(v) * (1.f / 64);
            float d = v - mu;
            float var = wave_sum(d * d) * (1.f / 64);
            xin[p * 64 + lane] = d * rsqrtf(var + 1e-5f) * g2[lane] + be2[lane];
        }
    }
}

// ---------------------------------------------------------------------------
// Inter-series GSL + GNN: one 320-thread (5-wave) block per (b,p).
// wave = variable n, lane = channel d. All weight reads now coalesced.
// ---------------------------------------------------------------------------
__global__ __launch_bounds__(320) void gnn_kernel(
    float* __restrict__ h,
    const float* __restrict__ Es1, const float* __restrict__ Es2,
    const float* __restrict__ Wd1t, const float* __restrict__ bd1,
    const float* __restrict__ Wd2t, const float* __restrict__ bd2,
    const float* __restrict__ Wg1, const float* __restrict__ bg1,
    const float* __restrict__ Wg2, const float* __restrict__ bg2,
    const float* __restrict__ gWt, const float* __restrict__ gb,
    const float* __restrict__ g3, const float* __restrict__ be3) {
    __shared__ float hs[5][64];
    __shared__ float ep1[5][16], ep2[5][16];
    __shared__ float Araw[5][8], As[5][8], A2s[5][8];
    __shared__ float t1s[5][64], t2s[5][64];

    const int bp = blockIdx.x;
    const int b = bp >> 4, p = bp & 15;
    const int n = threadIdx.x >> 6, lane = threadIdx.x & 63;
    float* hptr = h + (((b * CN + n) * CP + p) * CD);

    hs[n][lane] = hptr[lane];
    __syncthreads();

    // Ed (lane<16 keeps its own row; Wd*t coalesced within 64B)
    float a1 = 0.f, a2 = 0.f;
    if (lane < 16) {
        a1 = bd1[lane]; a2 = bd2[lane];
        for (int d = 0; d < 64; ++d) {
            a1 = fmaf(hs[n][d], Wd1t[d * 16 + lane], a1);
            a2 = fmaf(hs[n][d], Wd2t[d * 16 + lane], a2);
        }
    }
    // gates: relu(tanh([hh|Es] @ Wg.T + bg)) via full-wave reduction
    float p1 = hs[n][lane] * Wg1[lane] + ((lane < 16) ? Es1[n * 16 + lane] * Wg1[64 + lane] : 0.f);
    float p2 = hs[n][lane] * Wg2[lane] + ((lane < 16) ? Es2[n * 16 + lane] * Wg2[64 + lane] : 0.f);
    float gg1 = fmaxf(tanhf(wave_sum(p1) + bg1[0]), 0.f);
    float gg2 = fmaxf(tanhf(wave_sum(p2) + bg2[0]), 0.f);
    if (lane < 16) {
        ep1[n][lane] = Es1[n * 16 + lane] + gg1 * a1;
        ep2[n][lane] = Es2[n * 16 + lane] + gg2 * a2;
    }
    __syncthreads();

    // A = softmax(relu(Ep1 @ Ep2^T), axis=-1)
    if (lane < 5) {
        float e = 0.f;
#pragma unroll
        for (int k = 0; k < 16; ++k) e = fmaf(ep1[n][k], ep2[lane][k], e);
        Araw[n][lane] = fmaxf(e, 0.f);
    }
    __syncthreads();
    if (lane < 5) {
        float m = Araw[n][0];
#pragma unroll
        for (int j = 1; j < 5; ++j) m = fmaxf(m, Araw[n][j]);
        float l = 0.f;
#pragma unroll
        for (int j = 0; j < 5; ++j) l += __expf(Araw[n][j] - m);
        As[n][lane] = __expf(Araw[n][lane] - m) / l;
    }
    __syncthreads();
    if (lane < 5) {
        float a = 0.f;
#pragma unroll
        for (int l2 = 0; l2 < 5; ++l2) a = fmaf(As[n][l2], As[l2][lane], a);
        A2s[n][lane] = a;
    }
    __syncthreads();

    // t1 = A@hh, t2 = A^2@hh
    {
        float t1 = 0.f, t2 = 0.f;
#pragma unroll
        for (int m = 0; m < 5; ++m) {
            t1 = fmaf(As[n][m], hs[m][lane], t1);
            t2 = fmaf(A2s[n][m], hs[m][lane], t2);
        }
        t1s[n][lane] = t1;
        t2s[n][lane] = t2;
    }
    __syncthreads();

    // res = hh@gW0.T + t1@gW1.T + t2@gW2.T + (gb0+gb1+gb2)   (gWt coalesced)
    float res = gb[lane] + gb[64 + lane] + gb[128 + lane];
    for (int c = 0; c < 64; ++c) {
        res = fmaf(hs[n][c], gWt[c * 64 + lane], res);
        res = fmaf(t1s[n][c], gWt[4096 + c * 64 + lane], res);
        res = fmaf(t2s[n][c], gWt[8192 + c * 64 + lane], res);
    }
    float pre = hs[n][lane] + fmaxf(res, 0.f);

    // LN3 + write back
    float mu = wave_sum(pre) * (1.f / 64);
    float d = pre - mu;
    float var = wave_sum(d * d) * (1.f / 64);
    hptr[lane] = d * rsqrtf(var + 1e-5f) * g3[lane] + be3[lane];
}

// ---------------------------------------------------------------------------
// Head: 256 threads per (b,n); 1024-dot split across 4 waves, transposed
// (coalesced) ow1/ow2/ow3.
// ---------------------------------------------------------------------------
__global__ __launch_bounds__(256) void head_kernel(
    const float* __restrict__ h, const float* __restrict__ fp_wt, const float* __restrict__ fp_b,
    const float* __restrict__ q_omega, const float* __restrict__ q_alpha,
    const float* __restrict__ o1t, const float* __restrict__ ob1,
    const float* __restrict__ o2t, const float* __restrict__ ob2,
    const float* __restrict__ o3t, const float* __restrict__ ob3,
    float* __restrict__ out) {
    __shared__ float flat[1024];
    __shared__ float part[4][64];
    __shared__ float inp[80];
    __shared__ float h1s[64], h2s[64];
    const int row = blockIdx.x;  // b*5+n
    const int n = row % CN;
    const int t = threadIdx.x, wid = t >> 6, lane = t & 63;
    const float* src = h + row * CP * CD;

    for (int e = t; e < 1024; e += 256) flat[e] = src[e];
    __syncthreads();

    // fp-dot: wave wid covers j in [wid*256, wid*256+256)
    float a0 = 0.f, a1 = 0.f, a2 = 0.f, a3 = 0.f;
    const int j0 = wid * 256;
    for (int j = 0; j < 256; j += 4) {
        a0 = fmaf(flat[j0 + j],     fp_wt[(j0 + j) * 64 + lane],     a0);
        a1 = fmaf(flat[j0 + j + 1], fp_wt[(j0 + j + 1) * 64 + lane], a1);
        a2 = fmaf(flat[j0 + j + 2], fp_wt[(j0 + j + 2) * 64 + lane], a2);
        a3 = fmaf(flat[j0 + j + 3], fp_wt[(j0 + j + 3) * 64 + lane], a3);
    }
    part[wid][lane] = (a0 + a1) + (a2 + a3);
    if (t >= 64 && t < 80) {
        int i = t - 64;
        const float tt = (float)CL;
        inp[64 + i] = (i == 0) ? (q_omega[0] * tt + q_alpha[0])
                               : sinf(q_omega[i] * tt + q_alpha[i]);
    }
    __syncthreads();
    if (t < 64) inp[t] = fp_b[t] + ((part[0][t] + part[1][t]) + (part[2][t] + part[3][t]));
    __syncthreads();

    if (t < 64) {
        float a = ob1[n * 64 + t];
        for (int i = 0; i < 80; ++i) a = fmaf(inp[i], o1t[n * 5120 + i * 64 + t], a);
        h1s[t] = fmaxf(a, 0.f);
    }
    __syncthreads();
    if (t < 64) {
        float a = ob2[n * 64 + t];
        for (int i = 0; i < 64; ++i) a = fmaf(h1s[i], o2t[n * 4096 + i * 64 + t], a);
        h2s[t] = fmaxf(a, 0.f);
    }
    __syncthreads();
    if (t < CNC) {
        float a = ob3[n * CNC + t];
        for (int i = 0; i < 64; ++i) a = fmaf(h2s[i], o3t[n * 4096 + i * 64 + t], a);
        out[row * CNC + t] = a;
    }
}

// ---------------------------------------------------------------------------
extern "C" void kernel_launch(void* const* d_in, const int* in_sizes, int n_in,
                              void* d_out, int out_size, void* d_ws, size_t ws_size,
                              hipStream_t stream) {
    const float* x         = (const float*)d_in[0];
    const float* t_rel     = (const float*)d_in[1];
    const float* te_omega  = (const float*)d_in[2];
    const float* te_alpha  = (const float*)d_in[3];
    const float* mf_w1     = (const float*)d_in[4];
    const float* mf_b1     = (const float*)d_in[5];
    const float* mf_w2     = (const float*)d_in[6];
    const float* mf_b2     = (const float*)d_in[7];
    const float* pos_enc   = (const float*)d_in[8];
    const float* attn_in_w = (const float*)d_in[9];
    const float* attn_in_b = (const float*)d_in[10];
    const float* attn_out_w= (const float*)d_in[11];
    const float* attn_out_b= (const float*)d_in[12];
    const float* ln1_g     = (const float*)d_in[13];
    const float* ln1_b     = (const float*)d_in[14];
    const float* ffn_w1    = (const float*)d_in[15];
    const float* ffn_b1    = (const float*)d_in[16];
    const float* ffn_w2    = (const float*)d_in[17];
    const float* ffn_b2    = (const float*)d_in[18];
    const float* ln2_g     = (const float*)d_in[19];
    const float* ln2_b     = (const float*)d_in[20];
    const float* gsl_Es1   = (const float*)d_in[21];
    const float* gsl_Es2   = (const float*)d_in[22];
    const float* gsl_Wd1   = (const float*)d_in[23];
    const float* gsl_bd1   = (const float*)d_in[24];
    const float* gsl_Wd2   = (const float*)d_in[25];
    const float* gsl_bd2   = (const float*)d_in[26];
    const float* gsl_Wg1   = (const float*)d_in[27];
    const float* gsl_bg1   = (const float*)d_in[28];
    const float* gsl_Wg2   = (const float*)d_in[29];
    const float* gsl_bg2   = (const float*)d_in[30];
    const float* gnn_W     = (const float*)d_in[31];
    const float* gnn_b     = (const float*)d_in[32];
    const float* ln3_g     = (const float*)d_in[33];
    const float* ln3_b     = (const float*)d_in[34];
    const float* fp_w      = (const float*)d_in[35];
    const float* fp_b      = (const float*)d_in[36];
    const float* q_omega   = (const float*)d_in[37];
    const float* q_alpha   = (const float*)d_in[38];
    const float* ow1       = (const float*)d_in[39];
    const float* ob1       = (const float*)d_in[40];
    const float* ow2       = (const float*)d_in[41];
    const float* ob2       = (const float*)d_in[42];
    const float* ow3       = (const float*)d_in[43];
    const float* ob3       = (const float*)d_in[44];

    float* ws = (float*)d_ws;
    float* hbuf   = ws;                     // 655360
    float* base   = hbuf + 655360;          // 16*17*8*64 = 139264  [p][j][s][f]
    float* te_tab = base + 139264;          // 2048
    float* w1c16  = te_tab + 2048;          // 1088
    float* w2t    = w1c16 + 1088;           // 18496
    float* b2t    = w2t + 18496;            // 1088
    float* fp_wt  = b2t + 1088;             // 65536
    float* wit    = fp_wt + 65536;          // 24576
    float* wot    = wit + 24576;            // 8192
    float* fw1t   = wot + 8192;             // 16384
    float* fw2t   = fw1t + 16384;           // 16384
    float* gWt    = fw2t + 16384;           // 24576
    float* Wd1t   = gWt + 24576;            // 2048
    float* Wd2t   = Wd1t + 2048;            // 2048
    float* o1t    = Wd2t + 2048;            // 25600
    float* o2t    = o1t + 25600;            // 20480
    float* o3t    = o2t + 20480;            // 12480

    prep_kernel<<<256, 256, 0, stream>>>(
        mf_w1, mf_w2, mf_b2, fp_w, attn_in_w, attn_out_w, ffn_w1, ffn_w2,
        gnn_W, gsl_Wd1, gsl_Wd2, ow1, ow2, ow3,
        w1c16, w2t, b2t, fp_wt, wit, wot, fw1t, fw2t, gWt, Wd1t, Wd2t,
        o1t, o2t, o3t);

    prep2_kernel<<<CP * CS * CDIN, 64, 0, stream>>>(t_rel, te_omega, te_alpha,
                                                    mf_w1, mf_b1, base, te_tab);

    ttcn_kernel<<<1280, 512, 0, stream>>>(x, base, te_tab, w1c16,
                                          w2t, b2t, pos_enc, hbuf);

    for (int bk = 0; bk < 2; ++bk) {
        intra_kernel<<<CB * CN, 256, 0, stream>>>(
            hbuf,
            wit + bk * 12288, attn_in_b + bk * 192,
            wot + bk * 4096, attn_out_b + bk * 64,
            ln1_g + bk * 64, ln1_b + bk * 64,
            fw1t + bk * 8192, ffn_b1 + bk * 128,
            fw2t + bk * 8192, ffn_b2 + bk * 64,
            ln2_g + bk * 64, ln2_b + bk * 64);

        gnn_kernel<<<CB * CP, 320, 0, stream>>>(
            hbuf,
            gsl_Es1 + bk * CN * 16, gsl_Es2 + bk * CN * 16,
            Wd1t + bk * 1024, gsl_bd1 + bk * 16,
            Wd2t + bk * 1024, gsl_bd2 + bk * 16,
            gsl_Wg1 + bk * 80, gsl_bg1 + bk,
            gsl_Wg2 + bk * 80, gsl_bg2 + bk,
            gWt + bk * 12288, gnn_b + bk * 3 * 64,
            ln3_g + bk * 64, ln3_b + bk * 64);
    }

    head_kernel<<<CB * CN, 256, 0, stream>>>(hbuf, fp_wt, fp_b, q_omega, q_alpha,
                                             o1t, ob1, o2t, ob2, o3t, ob3,
                                             (float*)d_out);
}

// Round 7
// 463.205 us; speedup vs baseline: 1.5632x; 1.5632x over previous
//
#include <hip/hip_runtime.h>
#include <math.h>

// Model dims
#define CB 128   // batch
#define CN 5     // n_vars
#define CL 128   // seq len
#define CS 8     // patch size
#define CP 16    // n_patches
#define CD 64    // d_hidden
#define CDT 16   // d_time
#define CDIN 17  // DT+1
#define CNF 63   // D-1
#define CNC 39   // n_classes

__device__ __forceinline__ float wave_sum(float v) {
    v += __shfl_xor(v, 32);
    v += __shfl_xor(v, 16);
    v += __shfl_xor(v, 8);
    v += __shfl_xor(v, 4);
    v += __shfl_xor(v, 2);
    v += __shfl_xor(v, 1);
    return v;
}

// ---------------------------------------------------------------------------
// prep: all weight transposes, coalesced-read / scattered-write.
// ---------------------------------------------------------------------------
__global__ void prep_kernel(
    const float* __restrict__ mf_w1, const float* __restrict__ mf_w2,
    const float* __restrict__ mf_b2, const float* __restrict__ fp_w,
    const float* __restrict__ attn_in_w, const float* __restrict__ attn_out_w,
    const float* __restrict__ ffn_w1, const float* __restrict__ ffn_w2,
    const float* __restrict__ gnn_W, const float* __restrict__ gsl_Wd1,
    const float* __restrict__ gsl_Wd2,
    const float* __restrict__ ow1, const float* __restrict__ ow2,
    const float* __restrict__ ow3,
    float* __restrict__ w1c16, float* __restrict__ w2t, float* __restrict__ b2t,
    float* __restrict__ fp_wt, float* __restrict__ wit, float* __restrict__ wot,
    float* __restrict__ fw1t, float* __restrict__ fw2t,
    float* __restrict__ gWt, float* __restrict__ Wd1t, float* __restrict__ Wd2t,
    float* __restrict__ o1t, float* __restrict__ o2t, float* __restrict__ o3t) {
    int idx = blockIdx.x * 256 + threadIdx.x;
    if (idx < 65536) {                        // fp_wt[j*64+d] = fp_w[d][j]
        int d = idx >> 10, j = idx & 1023;
        fp_wt[j * 64 + d] = fp_w[idx];
    }
    if (idx < 18496) {                        // w2t[(k*17+j)*64+f] = w2[f][k][j]
        int f = idx / 289, rem = idx % 289;
        w2t[rem * 64 + f] = (f < CNF) ? mf_w2[idx] : 0.f;
    }
    if (idx < 1088) {                         // b2t[r*64+f] = b2[f][r]; w1c16[r*64+f] = w1[f][r][16]
        int f = idx / 17, r = idx % 17;
        b2t[r * 64 + f]   = (f < CNF) ? mf_b2[idx] : 0.f;
        w1c16[r * 64 + f] = (f < CNF) ? mf_w1[idx * 17 + 16] : 0.f;
    }
    if (idx < 24576) {                        // wit[bk][d*192+oc] = wi[bk][oc][d]
        int bk = idx / 12288, rem = idx % 12288;
        int oc = rem >> 6, d = rem & 63;
        wit[bk * 12288 + d * 192 + oc] = attn_in_w[idx];
    }
    if (idx < 8192) {                         // wot[bk][c*64+d] = wo[bk][d][c]
        int bk = idx >> 12, rem = idx & 4095;
        int d = rem >> 6, c = rem & 63;
        wot[bk * 4096 + c * 64 + d] = attn_out_w[idx];
    }
    if (idx < 16384) {                        // fw1t[bk][d*128+c] = fw1[bk][c][d]
        int bk = idx >> 13, rem = idx & 8191;
        int c = rem >> 6, d = rem & 63;
        fw1t[bk * 8192 + d * 128 + c] = ffn_w1[idx];
    }
    if (idx < 16384) {                        // fw2t[bk][c*64+d] = fw2[bk][d][c]
        int bk = idx >> 13, rem = idx & 8191;
        int d = rem >> 7, c = rem & 127;
        fw2t[bk * 8192 + c * 64 + d] = ffn_w2[idx];
    }
    if (idx < 24576) {                        // gWt[bk][m][c*64+o] = gW[bk][m][o][c]
        int bk = idx / 12288, rem = idx % 12288;
        int m = rem >> 12, r2 = rem & 4095;
        int o = r2 >> 6, c = r2 & 63;
        gWt[bk * 12288 + m * 4096 + c * 64 + o] = gnn_W[idx];
    }
    if (idx < 2048) {                         // Wd1t[bk][d*16+l] = Wd1[bk][l][d]
        int bk = idx >> 10, rem = idx & 1023;
        int l = rem >> 6, d = rem & 63;
        Wd1t[bk * 1024 + d * 16 + l] = gsl_Wd1[idx];
        Wd2t[bk * 1024 + d * 16 + l] = gsl_Wd2[idx];
    }
    if (idx < 25600) {                        // o1t[n][i*64+o] = ow1[n][o][i]
        int n = idx / 5120, rem = idx % 5120;
        int o = rem / 80, i = rem % 80;
        o1t[n * 5120 + i * 64 + o] = ow1[idx];
    }
    if (idx < 20480) {                        // o2t[n][i*64+o] = ow2[n][o][i]
        int n = idx >> 12, rem = idx & 4095;
        int o = rem >> 6, i = rem & 63;
        o2t[n * 4096 + i * 64 + o] = ow2[idx];
    }
    if (idx < 12480) {                        // o3t[n][i*64+o] = ow3[n][o][i], o<39
        int n = idx / 2496, rem = idx % 2496;
        int o = rem >> 6, i = rem & 63;
        o3t[n * 4096 + i * 64 + o] = ow3[idx];
    }
}

// ---------------------------------------------------------------------------
// prep2: t_rel is batch-invariant, so the te-part of TTCN phase A is shared
// by all B*N tokens. Emit base in [p][j][s][f] order and te_tab[p][s][k].
// ---------------------------------------------------------------------------
__global__ __launch_bounds__(64) void prep2_kernel(
    const float* __restrict__ t_rel, const float* __restrict__ omega, const float* __restrict__ alpha,
    const float* __restrict__ mf_w1, const float* __restrict__ mf_b1,
    float* __restrict__ base, float* __restrict__ te_tab) {
    const int blk = blockIdx.x;               // = (p*8+s)*17 + j
    const int j = blk % 17;
    const int ps = blk / 17;                  // p*8+s
    const int p = ps >> 3, s = ps & 7;
    const int f = threadIdx.x;

    const float t = t_rel[p * CS + s];        // row b=0
    float te[16];
#pragma unroll
    for (int i = 0; i < 16; ++i)
        te[i] = (i == 0) ? (omega[0] * t + alpha[0]) : sinf(omega[i] * t + alpha[i]);

    float acc = 0.f;
    if (f < CNF) {
        acc = mf_b1[f * 17 + j];
        const float* w = mf_w1 + (f * 17 + j) * 17;
#pragma unroll
        for (int i = 0; i < 16; ++i) acc = fmaf(te[i], w[i], acc);
    }
    base[((p * 17 + j) * 8 + s) * 64 + f] = acc;

    if (j == 0 && f < 16) te_tab[ps * 16 + f] = te[f];
}

// ---------------------------------------------------------------------------
// TTCN v3b: 512-thread blocks (8 waves = 8 tokens sharing one patch p).
// base/w1c/b2t/te in LDS. k in 4 chunks (live acc <= 40).
// FIX vs v3: __launch_bounds__(512,2) -- the (512,6) bound clamped VGPRs to
// 40 and spilled all accumulators to scratch (1 GB/dispatch HBM traffic).
// Occupancy check: (512,2) -> VGPR cap 256 (compiler needs ~90, no spill);
// actual residency LDS-limited at 3 blocks/CU = 24 waves/CU.
// ---------------------------------------------------------------------------
template <int K0, int KC>
__device__ __forceinline__ float ttcn_chunk(
    const float* __restrict__ w2t, const float* bse, const float* w1c,
    const float* b2s, const float* tes, const float v_s[8], int lane) {
    float lg[KC][8];
#pragma unroll
    for (int kk = 0; kk < KC; ++kk) {
        float bb = b2s[(K0 + kk) * 64 + lane];
#pragma unroll
        for (int s = 0; s < 8; ++s) lg[kk][s] = bb;
    }
#pragma unroll 1
    for (int j = 0; j < 17; ++j) {
        float w1 = w1c[j * 64 + lane];
        float h_s[8];
#pragma unroll
        for (int s = 0; s < 8; ++s)
            h_s[s] = fmaxf(fmaf(v_s[s], w1, bse[(j * 8 + s) * 64 + lane]), 0.f);
#pragma unroll
        for (int kk = 0; kk < KC; ++kk) {
            float w2 = w2t[((K0 + kk) * 17 + j) * 64 + lane];
#pragma unroll
            for (int s = 0; s < 8; ++s) lg[kk][s] = fmaf(h_s[s], w2, lg[kk][s]);
        }
    }
    float out = 0.f;
#pragma unroll
    for (int kk = 0; kk < KC; ++kk) {
        const int k = K0 + kk;
        float m = lg[kk][0];
#pragma unroll
        for (int s = 1; s < 8; ++s) m = fmaxf(m, lg[kk][s]);
        float l = 0.f, o = 0.f;
#pragma unroll
        for (int s = 0; s < 8; ++s) {
            float e = __expf(lg[kk][s] - m);
            l += e;
            o = fmaf(e, (k < 16) ? tes[s * 16 + k] : v_s[s], o);
        }
        out += o / l;
    }
    return out;
}

__global__ __launch_bounds__(512, 2) void ttcn_kernel(
    const float* __restrict__ x, const float* __restrict__ base,
    const float* __restrict__ te_tab, const float* __restrict__ w1c16,
    const float* __restrict__ w2t, const float* __restrict__ b2t,
    const float* __restrict__ pos_enc, float* __restrict__ hout) {
    __shared__ float bse[8704];    // [j][s][f]
    __shared__ float w1c[1088];    // [j][f]
    __shared__ float b2s[1088];    // [k][f]
    __shared__ float tes[128];     // [s][k]
    const int tid = threadIdx.x;
    const int p = blockIdx.x / 80, g = blockIdx.x % 80;

    // vectorized LDS staging (all sources 16B-aligned)
    {
        const float4* bsrc4 = (const float4*)(base + p * 8704);   // 2176 float4
        float4* bse4 = (float4*)bse;
        for (int i = tid; i < 2176; i += 512) bse4[i] = bsrc4[i];
        const float4* w1c4 = (const float4*)w1c16;                // 272
        const float4* b2t4 = (const float4*)b2t;                  // 272
        float4* dw = (float4*)w1c;
        float4* db = (float4*)b2s;
        if (tid < 272) { dw[tid] = w1c4[tid]; db[tid] = b2t4[tid]; }
        if (tid < 128) tes[tid] = te_tab[p * 128 + tid];
    }
    __syncthreads();

    const int wid = tid >> 6, lane = tid & 63;
    const int bn = g * 8 + wid;          // b*5+n
    const int tok = bn * 16 + p;

    float v_s[8];
    {
        const float4* xv = (const float4*)(x + tok * 8);
        float4 x0 = xv[0], x1 = xv[1];
        v_s[0] = x0.x; v_s[1] = x0.y; v_s[2] = x0.z; v_s[3] = x0.w;
        v_s[4] = x1.x; v_s[5] = x1.y; v_s[6] = x1.z; v_s[7] = x1.w;
    }

    float out = 0.f;
    out += ttcn_chunk<0, 5>(w2t, bse, w1c, b2s, tes, v_s, lane);
    out += ttcn_chunk<5, 4>(w2t, bse, w1c, b2s, tes, v_s, lane);
    out += ttcn_chunk<9, 4>(w2t, bse, w1c, b2s, tes, v_s, lane);
    out += ttcn_chunk<13, 4>(w2t, bse, w1c, b2s, tes, v_s, lane);

    float val = (lane < CNF) ? out : 1.0f;
    hout[tok * 64 + lane] = val + pos_enc[p * 64 + lane];
}

// ---------------------------------------------------------------------------
// Intra-series transformer block: one 256-thread block per (b,n) row.
// ---------------------------------------------------------------------------
__global__ __launch_bounds__(256) void intra_kernel(
    float* __restrict__ h,
    const float* __restrict__ wit, const float* __restrict__ bi,
    const float* __restrict__ wot, const float* __restrict__ bo,
    const float* __restrict__ g1, const float* __restrict__ be1,
    const float* __restrict__ fw1t, const float* __restrict__ fb1,
    const float* __restrict__ fw2t, const float* __restrict__ fb2,
    const float* __restrict__ g2, const float* __restrict__ be2) {
    __shared__ float xs[16][64];
    __shared__ float qs[16][64];
    __shared__ float ks[16][64];
    __shared__ float vs[16][64];
    __shared__ float sc[4][16][16];
    __shared__ float os[16][64];
    __shared__ float x1[16][64];
    __shared__ float fs[16][128];

    const int row = blockIdx.x;  // b*5+n
    float* xin = h + row * CP * CD;
    const int t = threadIdx.x;

    for (int e = t; e < 1024; e += 256) xs[e >> 6][e & 63] = xin[e];
    __syncthreads();

    // qkv: lane = out channel oc (192 active); xs broadcast, wit coalesced
    if (t < 192) {
        const int oc = t;
        float acc[16];
#pragma unroll
        for (int p = 0; p < 16; ++p) acc[p] = bi[oc];
        for (int d = 0; d < 64; ++d) {
            float w = wit[d * 192 + oc];
#pragma unroll
            for (int p = 0; p < 16; ++p) acc[p] = fmaf(xs[p][d], w, acc[p]);
        }
#pragma unroll
        for (int p = 0; p < 16; ++p) {
            if (oc < 64)       qs[p][oc] = acc[p];
            else if (oc < 128) ks[p][oc - 64] = acc[p];
            else               vs[p][oc - 128] = acc[p];
        }
    }
    __syncthreads();

    // scores (4 heads x 16 x 16)
    for (int e = t; e < 1024; e += 256) {
        int hh = e >> 8, i = (e >> 4) & 15, j = e & 15;
        float acc = 0.f;
        for (int d = 0; d < 16; ++d) acc = fmaf(qs[i][hh * 16 + d], ks[j][hh * 16 + d], acc);
        sc[hh][i][j] = acc * 0.25f;  // 1/sqrt(16)
    }
    __syncthreads();

    // softmax over j per (head,i)
    if (t < 64) {
        int hh = t >> 4, i = t & 15;
        float m = sc[hh][i][0];
#pragma unroll
        for (int j = 1; j < 16; ++j) m = fmaxf(m, sc[hh][i][j]);
        float e_[16];
        float l = 0.f;
#pragma unroll
        for (int j = 0; j < 16; ++j) { e_[j] = __expf(sc[hh][i][j] - m); l += e_[j]; }
        float inv = 1.f / l;
#pragma unroll
        for (int j = 0; j < 16; ++j) sc[hh][i][j] = e_[j] * inv;
    }
    __syncthreads();

    // attn out
    for (int e = t; e < 1024; e += 256) {
        int p = e >> 6, c = e & 63, hh = c >> 4;
        float acc = 0.f;
        for (int j = 0; j < 16; ++j) acc = fmaf(sc[hh][p][j], vs[j][c], acc);
        os[p][c] = acc;
    }
    __syncthreads();

    // proj + residual (wot coalesced, os broadcast)
    for (int e = t; e < 1024; e += 256) {
        int p = e >> 6, d = e & 63;
        float acc = bo[d];
        for (int c = 0; c < 64; ++c) acc = fmaf(os[p][c], wot[c * 64 + d], acc);
        x1[p][d] = acc + xs[p][d];
    }
    __syncthreads();

    // LN1
    {
        int w = t >> 6, lane = t & 63;
        for (int p = w; p < 16; p += 4) {
            float v = x1[p][lane];
            float mu = wave_sum(v) * (1.f / 64);
            float d = v - mu;
            float var = wave_sum(d * d) * (1.f / 64);
            x1[p][lane] = d * rsqrtf(var + 1e-5f) * g1[lane] + be1[lane];
        }
    }
    __syncthreads();

    // FFN1
    for (int e = t; e < 2048; e += 256) {
        int p = e >> 7, c = e & 127;
        float acc = fb1[c];
        for (int d = 0; d < 64; ++d) acc = fmaf(x1[p][d], fw1t[d * 128 + c], acc);
        fs[p][c] = fmaxf(acc, 0.f);
    }
    __syncthreads();

    // FFN2 + residual
    for (int e = t; e < 1024; e += 256) {
        int p = e >> 6, d = e & 63;
        float acc = fb2[d];
        for (int c = 0; c < 128; ++c) acc = fmaf(fs[p][c], fw2t[c * 64 + d], acc);
        os[p][d] = acc + x1[p][d];
    }
    __syncthreads();

    // LN2 + write back
    {
        int w = t >> 6, lane = t & 63;
        for (int p = w; p < 16; p += 4) {
            float v = os[p][lane];
            float mu = wave_sum(v) * (1.f / 64);
            float d = v - mu;
            float var = wave_sum(d * d) * (1.f / 64);
            xin[p * 64 + lane] = d * rsqrtf(var + 1e-5f) * g2[lane] + be2[lane];
        }
    }
}

// ---------------------------------------------------------------------------
// Inter-series GSL + GNN: one 320-thread (5-wave) block per (b,p).
// ---------------------------------------------------------------------------
__global__ __launch_bounds__(320) void gnn_kernel(
    float* __restrict__ h,
    const float* __restrict__ Es1, const float* __restrict__ Es2,
    const float* __restrict__ Wd1t, const float* __restrict__ bd1,
    const float* __restrict__ Wd2t, const float* __restrict__ bd2,
    const float* __restrict__ Wg1, const float* __restrict__ bg1,
    const float* __restrict__ Wg2, const float* __restrict__ bg2,
    const float* __restrict__ gWt, const float* __restrict__ gb,
    const float* __restrict__ g3, const float* __restrict__ be3) {
    __shared__ float hs[5][64];
    __shared__ float ep1[5][16], ep2[5][16];
    __shared__ float Araw[5][8], As[5][8], A2s[5][8];
    __shared__ float t1s[5][64], t2s[5][64];

    const int bp = blockIdx.x;
    const int b = bp >> 4, p = bp & 15;
    const int n = threadIdx.x >> 6, lane = threadIdx.x & 63;
    float* hptr = h + (((b * CN + n) * CP + p) * CD);

    hs[n][lane] = hptr[lane];
    __syncthreads();

    // Ed (lane<16 keeps its own row; Wd*t coalesced within 64B)
    float a1 = 0.f, a2 = 0.f;
    if (lane < 16) {
        a1 = bd1[lane]; a2 = bd2[lane];
        for (int d = 0; d < 64; ++d) {
            a1 = fmaf(hs[n][d], Wd1t[d * 16 + lane], a1);
            a2 = fmaf(hs[n][d], Wd2t[d * 16 + lane], a2);
        }
    }
    // gates: relu(tanh([hh|Es] @ Wg.T + bg)) via full-wave reduction
    float p1 = hs[n][lane] * Wg1[lane] + ((lane < 16) ? Es1[n * 16 + lane] * Wg1[64 + lane] : 0.f);
    float p2 = hs[n][lane] * Wg2[lane] + ((lane < 16) ? Es2[n * 16 + lane] * Wg2[64 + lane] : 0.f);
    float gg1 = fmaxf(tanhf(wave_sum(p1) + bg1[0]), 0.f);
    float gg2 = fmaxf(tanhf(wave_sum(p2) + bg2[0]), 0.f);
    if (lane < 16) {
        ep1[n][lane] = Es1[n * 16 + lane] + gg1 * a1;
        ep2[n][lane] = Es2[n * 16 + lane] + gg2 * a2;
    }
    __syncthreads();

    // A = softmax(relu(Ep1 @ Ep2^T), axis=-1)
    if (lane < 5) {
        float e = 0.f;
#pragma unroll
        for (int k = 0; k < 16; ++k) e = fmaf(ep1[n][k], ep2[lane][k], e);
        Araw[n][lane] = fmaxf(e, 0.f);
    }
    __syncthreads();
    if (lane < 5) {
        float m = Araw[n][0];
#pragma unroll
        for (int j = 1; j < 5; ++j) m = fmaxf(m, Araw[n][j]);
        float l = 0.f;
#pragma unroll
        for (int j = 0; j < 5; ++j) l += __expf(Araw[n][j] - m);
        As[n][lane] = __expf(Araw[n][lane] - m) / l;
    }
    __syncthreads();
    if (lane < 5) {
        float a = 0.f;
#pragma unroll
        for (int l2 = 0; l2 < 5; ++l2) a = fmaf(As[n][l2], As[l2][lane], a);
        A2s[n][lane] = a;
    }
    __syncthreads();

    // t1 = A@hh, t2 = A^2@hh
    {
        float t1 = 0.f, t2 = 0.f;
#pragma unroll
        for (int m = 0; m < 5; ++m) {
            t1 = fmaf(As[n][m], hs[m][lane], t1);
            t2 = fmaf(A2s[n][m], hs[m][lane], t2);
        }
        t1s[n][lane] = t1;
        t2s[n][lane] = t2;
    }
    __syncthreads();

    // res = hh@gW0.T + t1@gW1.T + t2@gW2.T + (gb0+gb1+gb2)   (gWt coalesced)
    float res = gb[lane] + gb[64 + lane] + gb[128 + lane];
    for (int c = 0; c < 64; ++c) {
        res = fmaf(hs[n][c], gWt[c * 64 + lane], res);
        res = fmaf(t1s[n][c], gWt[4096 + c * 64 + lane], res);
        res = fmaf(t2s[n][c], gWt[8192 + c * 64 + lane], res);
    }
    float pre = hs[n][lane] + fmaxf(res, 0.f);

    // LN3 + write back
    float mu = wave_sum(pre) * (1.f / 64);
    float d = pre - mu;
    float var = wave_sum(d * d) * (1.f / 64);
    hptr[lane] = d * rsqrtf(var + 1e-5f) * g3[lane] + be3[lane];
}

// ---------------------------------------------------------------------------
// Head: 256 threads per (b,n); 1024-dot split across 4 waves.
// ---------------------------------------------------------------------------
__global__ __launch_bounds__(256) void head_kernel(
    const float* __restrict__ h, const float* __restrict__ fp_wt, const float* __restrict__ fp_b,
    const float* __restrict__ q_omega, const float* __restrict__ q_alpha,
    const float* __restrict__ o1t, const float* __restrict__ ob1,
    const float* __restrict__ o2t, const float* __restrict__ ob2,
    const float* __restrict__ o3t, const float* __restrict__ ob3,
    float* __restrict__ out) {
    __shared__ float flat[1024];
    __shared__ float part[4][64];
    __shared__ float inp[80];
    __shared__ float h1s[64], h2s[64];
    const int row = blockIdx.x;  // b*5+n
    const int n = row % CN;
    const int t = threadIdx.x, wid = t >> 6, lane = t & 63;
    const float* src = h + row * CP * CD;

    for (int e = t; e < 1024; e += 256) flat[e] = src[e];
    __syncthreads();

    // fp-dot: wave wid covers j in [wid*256, wid*256+256)
    float a0 = 0.f, a1 = 0.f, a2 = 0.f, a3 = 0.f;
    const int j0 = wid * 256;
    for (int j = 0; j < 256; j += 4) {
        a0 = fmaf(flat[j0 + j],     fp_wt[(j0 + j) * 64 + lane],     a0);
        a1 = fmaf(flat[j0 + j + 1], fp_wt[(j0 + j + 1) * 64 + lane], a1);
        a2 = fmaf(flat[j0 + j + 2], fp_wt[(j0 + j + 2) * 64 + lane], a2);
        a3 = fmaf(flat[j0 + j + 3], fp_wt[(j0 + j + 3) * 64 + lane], a3);
    }
    part[wid][lane] = (a0 + a1) + (a2 + a3);
    if (t >= 64 && t < 80) {
        int i = t - 64;
        const float tt = (float)CL;
        inp[64 + i] = (i == 0) ? (q_omega[0] * tt + q_alpha[0])
                               : sinf(q_omega[i] * tt + q_alpha[i]);
    }
    __syncthreads();
    if (t < 64) inp[t] = fp_b[t] + ((part[0][t] + part[1][t]) + (part[2][t] + part[3][t]));
    __syncthreads();

    if (t < 64) {
        float a = ob1[n * 64 + t];
        for (int i = 0; i < 80; ++i) a = fmaf(inp[i], o1t[n * 5120 + i * 64 + t], a);
        h1s[t] = fmaxf(a, 0.f);
    }
    __syncthreads();
    if (t < 64) {
        float a = ob2[n * 64 + t];
        for (int i = 0; i < 64; ++i) a = fmaf(h1s[i], o2t[n * 4096 + i * 64 + t], a);
        h2s[t] = fmaxf(a, 0.f);
    }
    __syncthreads();
    if (t < CNC) {
        float a = ob3[n * CNC + t];
        for (int i = 0; i < 64; ++i) a = fmaf(h2s[i], o3t[n * 4096 + i * 64 + t], a);
        out[row * CNC + t] = a;
    }
}

// ---------------------------------------------------------------------------
extern "C" void kernel_launch(void* const* d_in, const int* in_sizes, int n_in,
                              void* d_out, int out_size, void* d_ws, size_t ws_size,
                              hipStream_t stream) {
    const float* x         = (const float*)d_in[0];
    const float* t_rel     = (const float*)d_in[1];
    const float* te_omega  = (const float*)d_in[2];
    const float* te_alpha  = (const float*)d_in[3];
    const float* mf_w1     = (const float*)d_in[4];
    const float* mf_b1     = (const float*)d_in[5];
    const float* mf_w2     = (const float*)d_in[6];
    const float* mf_b2     = (const float*)d_in[7];
    const float* pos_enc   = (const float*)d_in[8];
    const float* attn_in_w = (const float*)d_in[9];
    const float* attn_in_b = (const float*)d_in[10];
    const float* attn_out_w= (const float*)d_in[11];
    const float* attn_out_b= (const float*)d_in[12];
    const float* ln1_g     = (const float*)d_in[13];
    const float* ln1_b     = (const float*)d_in[14];
    const float* ffn_w1    = (const float*)d_in[15];
    const float* ffn_b1    = (const float*)d_in[16];
    const float* ffn_w2    = (const float*)d_in[17];
    const float* ffn_b2    = (const float*)d_in[18];
    const float* ln2_g     = (const float*)d_in[19];
    const float* ln2_b     = (const float*)d_in[20];
    const float* gsl_Es1   = (const float*)d_in[21];
    const float* gsl_Es2   = (const float*)d_in[22];
    const float* gsl_Wd1   = (const float*)d_in[23];
    const float* gsl_bd1   = (const float*)d_in[24];
    const float* gsl_Wd2   = (const float*)d_in[25];
    const float* gsl_bd2   = (const float*)d_in[26];
    const float* gsl_Wg1   = (const float*)d_in[27];
    const float* gsl_bg1   = (const float*)d_in[28];
    const float* gsl_Wg2   = (const float*)d_in[29];
    const float* gsl_bg2   = (const float*)d_in[30];
    const float* gnn_W     = (const float*)d_in[31];
    const float* gnn_b     = (const float*)d_in[32];
    const float* ln3_g     = (const float*)d_in[33];
    const float* ln3_b     = (const float*)d_in[34];
    const float* fp_w      = (const float*)d_in[35];
    const float* fp_b      = (const float*)d_in[36];
    const float* q_omega   = (const float*)d_in[37];
    const float* q_alpha   = (const float*)d_in[38];
    const float* ow1       = (const float*)d_in[39];
    const float* ob1       = (const float*)d_in[40];
    const float* ow2       = (const float*)d_in[41];
    const float* ob2       = (const float*)d_in[42];
    const float* ow3       = (const float*)d_in[43];
    const float* ob3       = (const float*)d_in[44];

    float* ws = (float*)d_ws;
    float* hbuf   = ws;                     // 655360
    float* base   = hbuf + 655360;          // 139264  [p][j][s][f]
    float* te_tab = base + 139264;          // 2048
    float* w1c16  = te_tab + 2048;          // 1088
    float* w2t    = w1c16 + 1088;           // 18496
    float* b2t    = w2t + 18496;            // 1088
    float* fp_wt  = b2t + 1088;             // 65536
    float* wit    = fp_wt + 65536;          // 24576
    float* wot    = wit + 24576;            // 8192
    float* fw1t   = wot + 8192;             // 16384
    float* fw2t   = fw1t + 16384;           // 16384
    float* gWt    = fw2t + 16384;           // 24576
    float* Wd1t   = gWt + 24576;            // 2048
    float* Wd2t   = Wd1t + 2048;            // 2048
    float* o1t    = Wd2t + 2048;            // 25600
    float* o2t    = o1t + 25600;            // 20480
    float* o3t    = o2t + 20480;            // 12480

    prep_kernel<<<256, 256, 0, stream>>>(
        mf_w1, mf_w2, mf_b2, fp_w, attn_in_w, attn_out_w, ffn_w1, ffn_w2,
        gnn_W, gsl_Wd1, gsl_Wd2, ow1, ow2, ow3,
        w1c16, w2t, b2t, fp_wt, wit, wot, fw1t, fw2t, gWt, Wd1t, Wd2t,
        o1t, o2t, o3t);

    prep2_kernel<<<CP * CS * CDIN, 64, 0, stream>>>(t_rel, te_omega, te_alpha,
                                                    mf_w1, mf_b1, base, te_tab);

    ttcn_kernel<<<1280, 512, 0, stream>>>(x, base, te_tab, w1c16,
                                          w2t, b2t, pos_enc, hbuf);

    for (int bk = 0; bk < 2; ++bk) {
        intra_kernel<<<CB * CN, 256, 0, stream>>>(
            hbuf,
            wit + bk * 12288, attn_in_b + bk * 192,
            wot + bk * 4096, attn_out_b + bk * 64,
            ln1_g + bk * 64, ln1_b + bk * 64,
            fw1t + bk * 8192, ffn_b1 + bk * 128,
            fw2t + bk * 8192, ffn_b2 + bk * 64,
            ln2_g + bk * 64, ln2_b + bk * 64);

        gnn_kernel<<<CB * CP, 320, 0, stream>>>(
            hbuf,
            gsl_Es1 + bk * CN * 16, gsl_Es2 + bk * CN * 16,
            Wd1t + bk * 1024, gsl_bd1 + bk * 16,
            Wd2t + bk * 1024, gsl_bd2 + bk * 16,
            gsl_Wg1 + bk * 80, gsl_bg1 + bk,
            gsl_Wg2 + bk * 80, gsl_bg2 + bk,
            gWt + bk * 12288, gnn_b + bk * 3 * 64,
            ln3_g + bk * 64, ln3_b + bk * 64);
    }

    head_kernel<<<CB * CN, 256, 0, stream>>>(hbuf, fp_wt, fp_b, q_omega, q_alpha,
                                             o1t, ob1, o2t, ob2, o3t, ob3,
                                             (float*)d_out);
}

// Round 11
// 463.024 us; speedup vs baseline: 1.5638x; 1.0004x over previous
//
#include <hip/hip_runtime.h>
#include <math.h>

// Model dims
#define CB 128   // batch
#define CN 5     // n_vars
#define CL 128   // seq len
#define CS 8     // patch size
#define CP 16    // n_patches
#define CD 64    // d_hidden
#define CDT 16   // d_time
#define CDIN 17  // DT+1
#define CNF 63   // D-1
#define CNC 39   // n_classes

__device__ __forceinline__ float wave_sum(float v) {
    v += __shfl_xor(v, 32);
    v += __shfl_xor(v, 16);
    v += __shfl_xor(v, 8);
    v += __shfl_xor(v, 4);
    v += __shfl_xor(v, 2);
    v += __shfl_xor(v, 1);
    return v;
}

__device__ __forceinline__ float dot4(float4 a, float4 b, float acc) {
    acc = fmaf(a.x, b.x, acc);
    acc = fmaf(a.y, b.y, acc);
    acc = fmaf(a.z, b.z, acc);
    acc = fmaf(a.w, b.w, acc);
    return acc;
}

// ---------------------------------------------------------------------------
// prep: weight transposes. "v" layouts interleave groups of 4 input-dim
// elements so consumers read one float4 (16B/lane, coalesced) per 4 MACs:
//   wv[ ((i>>2)*OUTS + o)*4 + (i&3) ] = w[o][i]
// ---------------------------------------------------------------------------
__global__ void prep_kernel(
    const float* __restrict__ mf_w1, const float* __restrict__ mf_w2,
    const float* __restrict__ mf_b2, const float* __restrict__ fp_w,
    const float* __restrict__ attn_in_w, const float* __restrict__ attn_out_w,
    const float* __restrict__ ffn_w1, const float* __restrict__ ffn_w2,
    const float* __restrict__ gnn_W, const float* __restrict__ gsl_Wd1,
    const float* __restrict__ gsl_Wd2,
    const float* __restrict__ ow1, const float* __restrict__ ow2,
    const float* __restrict__ ow3,
    float* __restrict__ w1c16, float* __restrict__ w2t, float* __restrict__ b2t,
    float* __restrict__ fpv, float* __restrict__ witv, float* __restrict__ wotv,
    float* __restrict__ fw1v, float* __restrict__ fw2v,
    float* __restrict__ gWv, float* __restrict__ Wd1v, float* __restrict__ Wd2v,
    float* __restrict__ o1v, float* __restrict__ o2v, float* __restrict__ o3v) {
    int idx = blockIdx.x * 256 + threadIdx.x;
    if (idx < 65536) {                        // fpv: j-groups of 4, out=d (64)
        int d = idx >> 10, j = idx & 1023;
        fpv[((j >> 2) * 64 + d) * 4 + (j & 3)] = fp_w[idx];
    }
    if (idx < 18496) {                        // w2t[(k*17+j)*64+f] = w2[f][k][j]
        int f = idx / 289, rem = idx % 289;
        w2t[rem * 64 + f] = (f < CNF) ? mf_w2[idx] : 0.f;
    }
    if (idx < 1088) {                         // b2t[r*64+f]=b2[f][r]; w1c16[r*64+f]=w1[f][r][16]
        int f = idx / 17, r = idx % 17;
        b2t[r * 64 + f]   = (f < CNF) ? mf_b2[idx] : 0.f;
        w1c16[r * 64 + f] = (f < CNF) ? mf_w1[idx * 17 + 16] : 0.f;
    }
    if (idx < 24576) {                        // witv: d-groups, out=oc (192)
        int bk = idx / 12288, rem = idx % 12288;
        int oc = rem >> 6, d = rem & 63;
        witv[bk * 12288 + ((d >> 2) * 192 + oc) * 4 + (d & 3)] = attn_in_w[idx];
    }
    if (idx < 8192) {                         // wotv: c-groups, out=d (64)
        int bk = idx >> 12, rem = idx & 4095;
        int d = rem >> 6, c = rem & 63;
        wotv[bk * 4096 + ((c >> 2) * 64 + d) * 4 + (c & 3)] = attn_out_w[idx];
    }
    if (idx < 16384) {                        // fw1v: d-groups, out=c (128)
        int bk = idx >> 13, rem = idx & 8191;
        int c = rem >> 6, d = rem & 63;
        fw1v[bk * 8192 + ((d >> 2) * 128 + c) * 4 + (d & 3)] = ffn_w1[idx];
    }
    if (idx < 16384) {                        // fw2v: c-groups (128), out=d (64)
        int bk = idx >> 13, rem = idx & 8191;
        int d = rem >> 7, c = rem & 127;
        fw2v[bk * 8192 + ((c >> 2) * 64 + d) * 4 + (c & 3)] = ffn_w2[idx];
    }
    if (idx < 24576) {                        // gWv: c-groups, out=o, per matrix m
        int bk = idx / 12288, rem = idx % 12288;
        int m = rem >> 12, r2 = rem & 4095;
        int o = r2 >> 6, c = r2 & 63;
        gWv[bk * 12288 + m * 4096 + ((c >> 2) * 64 + o) * 4 + (c & 3)] = gnn_W[idx];
    }
    if (idx < 2048) {                         // Wd1v/Wd2v: d-groups, out=l (16)
        int bk = idx >> 10, rem = idx & 1023;
        int l = rem >> 6, d = rem & 63;
        Wd1v[bk * 1024 + ((d >> 2) * 16 + l) * 4 + (d & 3)] = gsl_Wd1[idx];
        Wd2v[bk * 1024 + ((d >> 2) * 16 + l) * 4 + (d & 3)] = gsl_Wd2[idx];
    }
    if (idx < 25600) {                        // o1v: i-groups (80), out=o (64)
        int n = idx / 5120, rem = idx % 5120;
        int o = rem / 80, i = rem % 80;
        o1v[n * 5120 + ((i >> 2) * 64 + o) * 4 + (i & 3)] = ow1[idx];
    }
    if (idx < 20480) {                        // o2v: i-groups (64), out=o (64)
        int n = idx >> 12, rem = idx & 4095;
        int o = rem >> 6, i = rem & 63;
        o2v[n * 4096 + ((i >> 2) * 64 + o) * 4 + (i & 3)] = ow2[idx];
    }
    if (idx < 12480) {                        // o3v: i-groups (64), out=o (39, padded 64)
        int n = idx / 2496, rem = idx % 2496;
        int o = rem >> 6, i = rem & 63;
        o3v[n * 4096 + ((i >> 2) * 64 + o) * 4 + (i & 3)] = ow3[idx];
    }
}

// ---------------------------------------------------------------------------
// prep2: t_rel is batch-invariant; precompute per (p,s,j,f):
//   base = b1[f][j] + sum_{i<16} te[p,s,i]*w1[f][j][i]   (layout [p][j][s][f])
// and te_tab[p][s][k].
// ---------------------------------------------------------------------------
__global__ __launch_bounds__(64) void prep2_kernel(
    const float* __restrict__ t_rel, const float* __restrict__ omega, const float* __restrict__ alpha,
    const float* __restrict__ mf_w1, const float* __restrict__ mf_b1,
    float* __restrict__ base, float* __restrict__ te_tab) {
    const int blk = blockIdx.x;               // = (p*8+s)*17 + j
    const int j = blk % 17;
    const int ps = blk / 17;                  // p*8+s
    const int p = ps >> 3, s = ps & 7;
    const int f = threadIdx.x;

    const float t = t_rel[p * CS + s];        // row b=0
    float te[16];
#pragma unroll
    for (int i = 0; i < 16; ++i)
        te[i] = (i == 0) ? (omega[0] * t + alpha[0]) : sinf(omega[i] * t + alpha[i]);

    float acc = 0.f;
    if (f < CNF) {
        acc = mf_b1[f * 17 + j];
        const float* w = mf_w1 + (f * 17 + j) * 17;
#pragma unroll
        for (int i = 0; i < 16; ++i) acc = fmaf(te[i], w[i], acc);
    }
    base[((p * 17 + j) * 8 + s) * 64 + f] = acc;

    if (j == 0 && f < 16) te_tab[ps * 16 + f] = te[f];
}

// ---------------------------------------------------------------------------
// TTCN v4: NO LDS (base/w1c/b2t are L1/L2-resident -- staging was pure
// overhead and capped occupancy; common-mistake #7). 256-thread blocks =
// 4 independent waves, all sharing patch p (L1 locality on base/w2t).
// k in 2 chunks {9,8}: halves bse re-reads + h recompute vs 4 chunks.
// te_tab reads are wave-uniform -> scalar loads.
// ---------------------------------------------------------------------------
template <int K0, int KC>
__device__ __forceinline__ float ttcn_chunk(
    const float* __restrict__ w2t, const float* __restrict__ bse,
    const float* __restrict__ w1c, const float* __restrict__ b2t,
    const float* __restrict__ tes, const float v_s[8], int lane) {
    float lg[KC][8];
#pragma unroll
    for (int kk = 0; kk < KC; ++kk) {
        float bb = b2t[(K0 + kk) * 64 + lane];
#pragma unroll
        for (int s = 0; s < 8; ++s) lg[kk][s] = bb;
    }
#pragma unroll 1
    for (int j = 0; j < 17; ++j) {
        float w1 = w1c[j * 64 + lane];
        float h_s[8];
#pragma unroll
        for (int s = 0; s < 8; ++s)
            h_s[s] = fmaxf(fmaf(v_s[s], w1, bse[(j * 8 + s) * 64 + lane]), 0.f);
#pragma unroll
        for (int kk = 0; kk < KC; ++kk) {
            float w2 = w2t[((K0 + kk) * 17 + j) * 64 + lane];
#pragma unroll
            for (int s = 0; s < 8; ++s) lg[kk][s] = fmaf(h_s[s], w2, lg[kk][s]);
        }
    }
    float out = 0.f;
#pragma unroll
    for (int kk = 0; kk < KC; ++kk) {
        const int k = K0 + kk;
        float m = lg[kk][0];
#pragma unroll
        for (int s = 1; s < 8; ++s) m = fmaxf(m, lg[kk][s]);
        float l = 0.f, o = 0.f;
#pragma unroll
        for (int s = 0; s < 8; ++s) {
            float e = __expf(lg[kk][s] - m);
            l += e;
            o = fmaf(e, (k < 16) ? tes[s * 16 + k] : v_s[s], o);
        }
        out += o / l;
    }
    return out;
}

__global__ __launch_bounds__(256, 2) void ttcn_kernel(
    const float* __restrict__ x, const float* __restrict__ base,
    const float* __restrict__ te_tab, const float* __restrict__ w1c16,
    const float* __restrict__ w2t, const float* __restrict__ b2t,
    const float* __restrict__ pos_enc, float* __restrict__ hout) {
    const int tid = threadIdx.x, wid = tid >> 6, lane = tid & 63;
    const int p = blockIdx.x / 160, g = blockIdx.x % 160;
    const int bn = g * 4 + wid;          // b*5+n
    const int tok = bn * 16 + p;

    const float* bse = base + p * 8704;  // [j][s][f] for this p
    const float* tes = te_tab + p * 128; // [s][k]

    float v_s[8];
    {
        const float4* xv = (const float4*)(x + tok * 8);
        float4 x0 = xv[0], x1 = xv[1];
        v_s[0] = x0.x; v_s[1] = x0.y; v_s[2] = x0.z; v_s[3] = x0.w;
        v_s[4] = x1.x; v_s[5] = x1.y; v_s[6] = x1.z; v_s[7] = x1.w;
    }

    float out = 0.f;
    out += ttcn_chunk<0, 9>(w2t, bse, w1c16, b2t, tes, v_s, lane);
    out += ttcn_chunk<9, 8>(w2t, bse, w1c16, b2t, tes, v_s, lane);

    float val = (lane < CNF) ? out : 1.0f;
    hout[tok * 64 + lane] = val + pos_enc[p * 64 + lane];
}

// ---------------------------------------------------------------------------
// Intra-series transformer block: one 256-thread block per (b,n) row.
// All hot LDS reads are float4 (4x fewer LDS instructions than scalar).
// ---------------------------------------------------------------------------
__global__ __launch_bounds__(256) void intra_kernel(
    float* __restrict__ h,
    const float* __restrict__ witv, const float* __restrict__ bi,
    const float* __restrict__ wotv, const float* __restrict__ bo,
    const float* __restrict__ g1, const float* __restrict__ be1,
    const float* __restrict__ fw1v, const float* __restrict__ fb1,
    const float* __restrict__ fw2v, const float* __restrict__ fb2,
    const float* __restrict__ g2, const float* __restrict__ be2) {
    __shared__ __align__(16) float xs[16][64];
    __shared__ __align__(16) float qs[16][64];
    __shared__ __align__(16) float ks[16][64];
    __shared__ __align__(16) float vs[16][64];
    __shared__ __align__(16) float sc[4][16][16];
    __shared__ __align__(16) float os[16][64];
    __shared__ __align__(16) float x1[16][64];
    __shared__ __align__(16) float fs[16][128];

    const int row = blockIdx.x;  // b*5+n
    float* xin = h + row * CP * CD;
    const int t = threadIdx.x;

    const float4* witv4 = (const float4*)witv;
    const float4* wotv4 = (const float4*)wotv;
    const float4* fw1v4 = (const float4*)fw1v;
    const float4* fw2v4 = (const float4*)fw2v;

    {   // stage x (float4)
        float4* xs4 = (float4*)&xs[0][0];
        const float4* xin4 = (const float4*)xin;
        if (t < 256) xs4[t] = xin4[t];
    }
    __syncthreads();

    // qkv: thread = out channel oc (192 active); w loads coalesced float4
    if (t < 192) {
        const int oc = t;
        float acc[16];
#pragma unroll
        for (int p = 0; p < 16; ++p) acc[p] = bi[oc];
        const float4* xs4 = (const float4*)&xs[0][0];
        for (int d4 = 0; d4 < 16; ++d4) {
            float4 wv = witv4[d4 * 192 + oc];
#pragma unroll
            for (int p = 0; p < 16; ++p) acc[p] = dot4(xs4[p * 16 + d4], wv, acc[p]);
        }
#pragma unroll
        for (int p = 0; p < 16; ++p) {
            if (oc < 64)       qs[p][oc] = acc[p];
            else if (oc < 128) ks[p][oc - 64] = acc[p];
            else               vs[p][oc - 128] = acc[p];
        }
    }
    __syncthreads();

    // scores (4 heads x 16 x 16), float4 dot over head-dim 16
    for (int e = t; e < 1024; e += 256) {
        int hh = e >> 8, i = (e >> 4) & 15, j = e & 15;
        const float4* q4 = (const float4*)&qs[i][hh * 16];
        const float4* k4 = (const float4*)&ks[j][hh * 16];
        float acc = 0.f;
#pragma unroll
        for (int d4 = 0; d4 < 4; ++d4) acc = dot4(q4[d4], k4[d4], acc);
        sc[hh][i][j] = acc * 0.25f;  // 1/sqrt(16)
    }
    __syncthreads();

    // softmax over j per (head,i)
    if (t < 64) {
        int hh = t >> 4, i = t & 15;
        float m = sc[hh][i][0];
#pragma unroll
        for (int j = 1; j < 16; ++j) m = fmaxf(m, sc[hh][i][j]);
        float e_[16];
        float l = 0.f;
#pragma unroll
        for (int j = 0; j < 16; ++j) { e_[j] = __expf(sc[hh][i][j] - m); l += e_[j]; }
        float inv = 1.f / l;
#pragma unroll
        for (int j = 0; j < 16; ++j) sc[hh][i][j] = e_[j] * inv;
    }
    __syncthreads();

    // attn out: sc read as float4, vs scalar (stride-64, unvectorizable)
    for (int e = t; e < 1024; e += 256) {
        int p = e >> 6, c = e & 63, hh = c >> 4;
        const float4* s4 = (const float4*)&sc[hh][p][0];
        float acc = 0.f;
#pragma unroll
        for (int j4 = 0; j4 < 4; ++j4) {
            float4 sv = s4[j4];
            acc = fmaf(sv.x, vs[j4 * 4 + 0][c], acc);
            acc = fmaf(sv.y, vs[j4 * 4 + 1][c], acc);
            acc = fmaf(sv.z, vs[j4 * 4 + 2][c], acc);
            acc = fmaf(sv.w, vs[j4 * 4 + 3][c], acc);
        }
        os[p][c] = acc;
    }
    __syncthreads();

    // proj + residual
    for (int e = t; e < 1024; e += 256) {
        int p = e >> 6, d = e & 63;
        const float4* os4 = (const float4*)&os[p][0];
        float acc = bo[d];
#pragma unroll
        for (int c4 = 0; c4 < 16; ++c4) acc = dot4(os4[c4], wotv4[c4 * 64 + d], acc);
        x1[p][d] = acc + xs[p][d];
    }
    __syncthreads();

    // LN1
    {
        int w = t >> 6, lane = t & 63;
        for (int p = w; p < 16; p += 4) {
            float v = x1[p][lane];
            float mu = wave_sum(v) * (1.f / 64);
            float d = v - mu;
            float var = wave_sum(d * d) * (1.f / 64);
            x1[p][lane] = d * rsqrtf(var + 1e-5f) * g1[lane] + be1[lane];
        }
    }
    __syncthreads();

    // FFN1
    for (int e = t; e < 2048; e += 256) {
        int p = e >> 7, c = e & 127;
        const float4* x14 = (const float4*)&x1[p][0];
        float acc = fb1[c];
#pragma unroll
        for (int d4 = 0; d4 < 16; ++d4) acc = dot4(x14[d4], fw1v4[d4 * 128 + c], acc);
        fs[p][c] = fmaxf(acc, 0.f);
    }
    __syncthreads();

    // FFN2 + residual
    for (int e = t; e < 1024; e += 256) {
        int p = e >> 6, d = e & 63;
        const float4* fs4 = (const float4*)&fs[p][0];
        float acc = fb2[d];
#pragma unroll
        for (int c4 = 0; c4 < 32; ++c4) acc = dot4(fs4[c4], fw2v4[c4 * 64 + d], acc);
        os[p][d] = acc + x1[p][d];
    }
    __syncthreads();

    // LN2 + write back
    {
        int w = t >> 6, lane = t & 63;
        for (int p = w; p < 16; p += 4) {
            float v = os[p][lane];
            float mu = wave_sum(v) * (1.f / 64);
            float d = v - mu;
            float var = wave_sum(d * d) * (1.f / 64);
            xin[p * 64 + lane] = d * rsqrtf(var + 1e-5f) * g2[lane] + be2[lane];
        }
    }
}

// ---------------------------------------------------------------------------
// Inter-series GSL + GNN: one 320-thread (5-wave) block per (b,p).
// float4 LDS reads in the two matvec loops.
// ---------------------------------------------------------------------------
__global__ __launch_bounds__(320) void gnn_kernel(
    float* __restrict__ h,
    const float* __restrict__ Es1, const float* __restrict__ Es2,
    const float* __restrict__ Wd1v, const float* __restrict__ bd1,
    const float* __restrict__ Wd2v, const float* __restrict__ bd2,
    const float* __restrict__ Wg1, const float* __restrict__ bg1,
    const float* __restrict__ Wg2, const float* __restrict__ bg2,
    const float* __restrict__ gWv, const float* __restrict__ gb,
    const float* __restrict__ g3, const float* __restrict__ be3) {
    __shared__ __align__(16) float hs[5][64];
    __shared__ __align__(16) float t1s[5][64], t2s[5][64];
    __shared__ float ep1[5][16], ep2[5][16];
    __shared__ float Araw[5][8], As[5][8], A2s[5][8];

    const int bp = blockIdx.x;
    const int b = bp >> 4, p = bp & 15;
    const int n = threadIdx.x >> 6, lane = threadIdx.x & 63;
    float* hptr = h + (((b * CN + n) * CP + p) * CD);

    const float4* Wd1v4 = (const float4*)Wd1v;
    const float4* Wd2v4 = (const float4*)Wd2v;
    const float4* gWv4  = (const float4*)gWv;

    hs[n][lane] = hptr[lane];
    __syncthreads();

    // Ed (lane<16); float4 over d
    float a1 = 0.f, a2 = 0.f;
    if (lane < 16) {
        a1 = bd1[lane]; a2 = bd2[lane];
        const float4* hs4 = (const float4*)&hs[n][0];
#pragma unroll
        for (int d4 = 0; d4 < 16; ++d4) {
            float4 hv = hs4[d4];
            a1 = dot4(hv, Wd1v4[d4 * 16 + lane], a1);
            a2 = dot4(hv, Wd2v4[d4 * 16 + lane], a2);
        }
    }
    // gates: relu(tanh([hh|Es] @ Wg.T + bg)) via full-wave reduction
    float p1 = hs[n][lane] * Wg1[lane] + ((lane < 16) ? Es1[n * 16 + lane] * Wg1[64 + lane] : 0.f);
    float p2 = hs[n][lane] * Wg2[lane] + ((lane < 16) ? Es2[n * 16 + lane] * Wg2[64 + lane] : 0.f);
    float gg1 = fmaxf(tanhf(wave_sum(p1) + bg1[0]), 0.f);
    float gg2 = fmaxf(tanhf(wave_sum(p2) + bg2[0]), 0.f);
    if (lane < 16) {
        ep1[n][lane] = Es1[n * 16 + lane] + gg1 * a1;
        ep2[n][lane] = Es2[n * 16 + lane] + gg2 * a2;
    }
    __syncthreads();

    // A = softmax(relu(Ep1 @ Ep2^T), axis=-1)
    if (lane < 5) {
        float e = 0.f;
#pragma unroll
        for (int k = 0; k < 16; ++k) e = fmaf(ep1[n][k], ep2[lane][k], e);
        Araw[n][lane] = fmaxf(e, 0.f);
    }
    __syncthreads();
    if (lane < 5) {
        float m = Araw[n][0];
#pragma unroll
        for (int j = 1; j < 5; ++j) m = fmaxf(m, Araw[n][j]);
        float l = 0.f;
#pragma unroll
        for (int j = 0; j < 5; ++j) l += __expf(Araw[n][j] - m);
        As[n][lane] = __expf(Araw[n][lane] - m) / l;
    }
    __syncthreads();
    if (lane < 5) {
        float a = 0.f;
#pragma unroll
        for (int l2 = 0; l2 < 5; ++l2) a = fmaf(As[n][l2], As[l2][lane], a);
        A2s[n][lane] = a;
    }
    __syncthreads();

    // t1 = A@hh, t2 = A^2@hh
    {
        float t1 = 0.f, t2 = 0.f;
#pragma unroll
        for (int m = 0; m < 5; ++m) {
            t1 = fmaf(As[n][m], hs[m][lane], t1);
            t2 = fmaf(A2s[n][m], hs[m][lane], t2);
        }
        t1s[n][lane] = t1;
        t2s[n][lane] = t2;
    }
    __syncthreads();

    // res = hh@gW0.T + t1@gW1.T + t2@gW2.T + Σgb   (float4 LDS reads)
    float res = gb[lane] + gb[64 + lane] + gb[128 + lane];
    {
        const float4* hs4 = (const float4*)&hs[n][0];
        const float4* t14 = (const float4*)&t1s[n][0];
        const float4* t24 = (const float4*)&t2s[n][0];
#pragma unroll
        for (int c4 = 0; c4 < 16; ++c4) {
            res = dot4(hs4[c4], gWv4[c4 * 64 + lane], res);
            res = dot4(t14[c4], gWv4[1024 + c4 * 64 + lane], res);
            res = dot4(t24[c4], gWv4[2048 + c4 * 64 + lane], res);
        }
    }
    float pre = hs[n][lane] + fmaxf(res, 0.f);

    // LN3 + write back
    float mu = wave_sum(pre) * (1.f / 64);
    float d = pre - mu;
    float var = wave_sum(d * d) * (1.f / 64);
    hptr[lane] = d * rsqrtf(var + 1e-5f) * g3[lane] + be3[lane];
}

// ---------------------------------------------------------------------------
// Head: 256 threads per (b,n); float4 everywhere.
// ---------------------------------------------------------------------------
__global__ __launch_bounds__(256) void head_kernel(
    const float* __restrict__ h, const float* __restrict__ fpv, const float* __restrict__ fp_b,
    const float* __restrict__ q_omega, const float* __restrict__ q_alpha,
    const float* __restrict__ o1v, const float* __restrict__ ob1,
    const float* __restrict__ o2v, const float* __restrict__ ob2,
    const float* __restrict__ o3v, const float* __restrict__ ob3,
    float* __restrict__ out) {
    __shared__ __align__(16) float flat[1024];
    __shared__ __align__(16) float inp[80];
    __shared__ __align__(16) float h1s[64], h2s[64];
    __shared__ float part[4][64];
    const int row = blockIdx.x;  // b*5+n
    const int n = row % CN;
    const int t = threadIdx.x, wid = t >> 6, lane = t & 63;
    const float* src = h + row * CP * CD;

    const float4* fpv4 = (const float4*)fpv;
    const float4* o1v4 = (const float4*)o1v;
    const float4* o2v4 = (const float4*)o2v;
    const float4* o3v4 = (const float4*)o3v;

    {
        float4* flat4 = (float4*)flat;
        const float4* src4 = (const float4*)src;
        if (t < 256) flat4[t] = src4[t];
    }
    __syncthreads();

    // fp-dot: wave wid covers j4 in [wid*64, wid*64+64)
    {
        const float4* flat4 = (const float4*)flat;
        float a0 = 0.f;
        const int j40 = wid * 64;
        for (int j4 = 0; j4 < 64; ++j4)
            a0 = dot4(flat4[j40 + j4], fpv4[(j40 + j4) * 64 + lane], a0);
        part[wid][lane] = a0;
    }
    if (t >= 64 && t < 80) {
        int i = t - 64;
        const float tt = (float)CL;
        inp[64 + i] = (i == 0) ? (q_omega[0] * tt + q_alpha[0])
                               : sinf(q_omega[i] * tt + q_alpha[i]);
    }
    __syncthreads();
    if (t < 64) inp[t] = fp_b[t] + ((part[0][t] + part[1][t]) + (part[2][t] + part[3][t]));
    __syncthreads();

    if (t < 64) {
        const float4* inp4 = (const float4*)inp;
        float a = ob1[n * 64 + t];
#pragma unroll
        for (int i4 = 0; i4 < 20; ++i4) a = dot4(inp4[i4], o1v4[n * 1280 + i4 * 64 + t], a);
        h1s[t] = fmaxf(a, 0.f);
    }
    __syncthreads();
    if (t < 64) {
        const float4* h14 = (const float4*)h1s;
        float a = ob2[n * 64 + t];
#pragma unroll
        for (int i4 = 0; i4 < 16; ++i4) a = dot4(h14[i4], o2v4[n * 1024 + i4 * 64 + t], a);
        h2s[t] = fmaxf(a, 0.f);
    }
    __syncthreads();
    if (t < CNC) {
        const float4* h24 = (const float4*)h2s;
        float a = ob3[n * CNC + t];
#pragma unroll
        for (int i4 = 0; i4 < 16; ++i4) a = dot4(h24[i4], o3v4[n * 1024 + i4 * 64 + t], a);
        out[row * CNC + t] = a;
    }
}

// ---------------------------------------------------------------------------
extern "C" void kernel_launch(void* const* d_in, const int* in_sizes, int n_in,
                              void* d_out, int out_size, void* d_ws, size_t ws_size,
                              hipStream_t stream) {
    const float* x         = (const float*)d_in[0];
    const float* t_rel     = (const float*)d_in[1];
    const float* te_omega  = (const float*)d_in[2];
    const float* te_alpha  = (const float*)d_in[3];
    const float* mf_w1     = (const float*)d_in[4];
    const float* mf_b1     = (const float*)d_in[5];
    const float* mf_w2     = (const float*)d_in[6];
    const float* mf_b2     = (const float*)d_in[7];
    const float* pos_enc   = (const float*)d_in[8];
    const float* attn_in_w = (const float*)d_in[9];
    const float* attn_in_b = (const float*)d_in[10];
    const float* attn_out_w= (const float*)d_in[11];
    const float* attn_out_b= (const float*)d_in[12];
    const float* ln1_g     = (const float*)d_in[13];
    const float* ln1_b     = (const float*)d_in[14];
    const float* ffn_w1    = (const float*)d_in[15];
    const float* ffn_b1    = (const float*)d_in[16];
    const float* ffn_w2    = (const float*)d_in[17];
    const float* ffn_b2    = (const float*)d_in[18];
    const float* ln2_g     = (const float*)d_in[19];
    const float* ln2_b     = (const float*)d_in[20];
    const float* gsl_Es1   = (const float*)d_in[21];
    const float* gsl_Es2   = (const float*)d_in[22];
    const float* gsl_Wd1   = (const float*)d_in[23];
    const float* gsl_bd1   = (const float*)d_in[24];
    const float* gsl_Wd2   = (const float*)d_in[25];
    const float* gsl_bd2   = (const float*)d_in[26];
    const float* gsl_Wg1   = (const float*)d_in[27];
    const float* gsl_bg1   = (const float*)d_in[28];
    const float* gsl_Wg2   = (const float*)d_in[29];
    const float* gsl_bg2   = (const float*)d_in[30];
    const float* gnn_W     = (const float*)d_in[31];
    const float* gnn_b     = (const float*)d_in[32];
    const float* ln3_g     = (const float*)d_in[33];
    const float* ln3_b     = (const float*)d_in[34];
    const float* fp_w      = (const float*)d_in[35];
    const float* fp_b      = (const float*)d_in[36];
    const float* q_omega   = (const float*)d_in[37];
    const float* q_alpha   = (const float*)d_in[38];
    const float* ow1       = (const float*)d_in[39];
    const float* ob1       = (const float*)d_in[40];
    const float* ow2       = (const float*)d_in[41];
    const float* ob2       = (const float*)d_in[42];
    const float* ow3       = (const float*)d_in[43];
    const float* ob3       = (const float*)d_in[44];

    float* ws = (float*)d_ws;
    float* hbuf   = ws;                     // 655360
    float* base   = hbuf + 655360;          // 139264  [p][j][s][f]
    float* te_tab = base + 139264;          // 2048
    float* w1c16  = te_tab + 2048;          // 1088
    float* w2t    = w1c16 + 1088;           // 18496
    float* b2t    = w2t + 18496;            // 1088
    float* fpv    = b2t + 1088;             // 65536
    float* witv   = fpv + 65536;            // 24576
    float* wotv   = witv + 24576;           // 8192
    float* fw1v   = wotv + 8192;            // 16384
    float* fw2v   = fw1v + 16384;           // 16384
    float* gWv    = fw2v + 16384;           // 24576
    float* Wd1v   = gWv + 24576;            // 2048
    float* Wd2v   = Wd1v + 2048;            // 2048
    float* o1v    = Wd2v + 2048;            // 25600
    float* o2v    = o1v + 25600;            // 20480
    float* o3v    = o2v + 20480;            // 12480

    prep_kernel<<<256, 256, 0, stream>>>(
        mf_w1, mf_w2, mf_b2, fp_w, attn_in_w, attn_out_w, ffn_w1, ffn_w2,
        gnn_W, gsl_Wd1, gsl_Wd2, ow1, ow2, ow3,
        w1c16, w2t, b2t, fpv, witv, wotv, fw1v, fw2v, gWv, Wd1v, Wd2v,
        o1v, o2v, o3v);

    prep2_kernel<<<CP * CS * CDIN, 64, 0, stream>>>(t_rel, te_omega, te_alpha,
                                                    mf_w1, mf_b1, base, te_tab);

    ttcn_kernel<<<CP * 160, 256, 0, stream>>>(x, base, te_tab, w1c16,
                                              w2t, b2t, pos_enc, hbuf);

    for (int bk = 0; bk < 2; ++bk) {
        intra_kernel<<<CB * CN, 256, 0, stream>>>(
            hbuf,
            witv + bk * 12288, attn_in_b + bk * 192,
            wotv + bk * 4096, attn_out_b + bk * 64,
            ln1_g + bk * 64, ln1_b + bk * 64,
            fw1v + bk * 8192, ffn_b1 + bk * 128,
            fw2v + bk * 8192, ffn_b2 + bk * 64,
            ln2_g + bk * 64, ln2_b + bk * 64);

        gnn_kernel<<<CB * CP, 320, 0, stream>>>(
            hbuf,
            gsl_Es1 + bk * CN * 16, gsl_Es2 + bk * CN * 16,
            Wd1v + bk * 1024, gsl_bd1 + bk * 16,
            Wd2v + bk * 1024, gsl_bd2 + bk * 16,
            gsl_Wg1 + bk * 80, gsl_bg1 + bk,
            gsl_Wg2 + bk * 80, gsl_bg2 + bk,
            gWv + bk * 12288, gnn_b + bk * 3 * 64,
            ln3_g + bk * 64, ln3_b + bk * 64);
    }

    head_kernel<<<CB * CN, 256, 0, stream>>>(hbuf, fpv, fp_b, q_omega, q_alpha,
                                             o1v, ob1, o2v, ob2, o3v, ob3,
                                             (float*)d_out);
}